// Round 18
// baseline (613.501 us; speedup 1.0000x reference)
//
#include <hip/hip_runtime.h>
#include <hip/hip_bf16.h>
#include <math.h>

// Problem constants (fixed by the reference)
#define NN       10000      // nodes
#define F_IN     128
#define HID      300
#define H1       5
#define H3       3
#define NCLS     40
#define HC1      (H1*HID)   // 1500
#define KPAD     1536       // padded K / activation row stride (bf16)
#define HS12     304        // head col stride, layers 1-2 (300+4, mult of 16)
#define NL12     1520       // live padded cols layers 1-2 (5*304)
#define HS3      48         // head col stride, layer 3 (40+8, mult of 16)
#define NL3      144        // live padded cols layer 3 (3*48)
#define LD3      160        // layer-3 row stride
#define NEG_SLOPE 0.2f
#define EPSV     1e-16f

typedef __attribute__((ext_vector_type(8))) short bf16x8;
typedef __attribute__((ext_vector_type(8))) unsigned short u16x8;
typedef __attribute__((ext_vector_type(4))) float f32x4;

__device__ inline unsigned short f2bf(float f) {
  unsigned int u = __builtin_bit_cast(unsigned int, f);
  unsigned int r = (u + 0x7FFFu + ((u >> 16) & 1u)) >> 16;   // RNE
  return (unsigned short)r;
}
__device__ inline float bf2f(unsigned short s) {
  unsigned int u = ((unsigned int)s) << 16;
  return __builtin_bit_cast(float, u);
}

// async 16B/lane global->LDS (lds dest = wave-uniform base + lane*16)
__device__ __forceinline__ void gl2lds16(const unsigned short* g, unsigned short* l) {
  __builtin_amdgcn_global_load_lds(
      (const __attribute__((address_space(1))) unsigned int*)(const void*)g,
      (__attribute__((address_space(3))) unsigned int*)(void*)l, 16, 0, 0);
}

// ---------------------------------------------------------------------------
// CSR build
// ---------------------------------------------------------------------------
__global__ void k_count(const int* __restrict__ ei, int* __restrict__ counts,
                        int E0, int Etot) {
  int e = blockIdx.x * 256 + threadIdx.x;
  if (e >= Etot) return;
  int dst = (e < E0) ? ei[E0 + e] : (e - E0);
  atomicAdd(&counts[dst], 1);
}

__global__ __launch_bounds__(256) void k_scan(const int* __restrict__ counts,
                                              int* __restrict__ offsets,
                                              int* __restrict__ cursor,
                                              int N, int Etot) {
  __shared__ int sh[256];
  const int CH = 40;  // 256*40 = 10240 >= N
  int t = threadIdx.x;
  int base = t * CH;
  int s = 0;
  for (int i = 0; i < CH; i++) {
    int idx = base + i;
    if (idx < N) s += counts[idx];
  }
  sh[t] = s;
  __syncthreads();
  for (int d = 1; d < 256; d <<= 1) {
    int v = (t >= d) ? sh[t - d] : 0;
    __syncthreads();
    sh[t] += v;
    __syncthreads();
  }
  int run = sh[t] - s;  // exclusive prefix
  for (int i = 0; i < CH; i++) {
    int idx = base + i;
    if (idx < N) {
      offsets[idx] = run;
      cursor[idx] = run;
      run += counts[idx];
    }
  }
  if (t == 0) offsets[N] = Etot;
}

__global__ void k_scatter(const int* __restrict__ ei, int* __restrict__ cursor,
                          int* __restrict__ csr_src, int E0, int Etot) {
  int e = blockIdx.x * 256 + threadIdx.x;
  if (e >= Etot) return;
  int src, dst;
  if (e < E0) { src = ei[e]; dst = ei[E0 + e]; }
  else        { src = dst = e - E0; }
  int pos = atomicAdd(&cursor[dst], 1);
  csr_src[pos] = src;
}

// ---------------------------------------------------------------------------
// fp32 -> bf16 cast (x input)
// ---------------------------------------------------------------------------
__global__ void k_cvt(const float* __restrict__ in, unsigned short* __restrict__ out,
                      int R, int C, int Cpad) {
  long long idx = (long long)blockIdx.x * 256 + threadIdx.x;
  if (idx >= (long long)R * Cpad) return;
  int r = (int)(idx / Cpad), c = (int)(idx - (long long)r * Cpad);
  out[idx] = (c < C) ? f2bf(in[(size_t)r * C + c]) : 0;
}

// ---------------------------------------------------------------------------
// Preprocessing mega-kernel: z<3 = weight transpose jobs (head-pad remap both
// dims); z==3 = att-vector padding for all 3 layers.
// ---------------------------------------------------------------------------
__global__ __launch_bounds__(256) void k_prep(
    const float* __restrict__ W1, const float* __restrict__ W2,
    const float* __restrict__ W3,
    unsigned short* __restrict__ o1, unsigned short* __restrict__ o2,
    unsigned short* __restrict__ o3,
    const float* __restrict__ as1, const float* __restrict__ ad1,
    const float* __restrict__ as2, const float* __restrict__ ad2,
    const float* __restrict__ as3, const float* __restrict__ ad3,
    float* __restrict__ ps1, float* __restrict__ pd1,
    float* __restrict__ ps2, float* __restrict__ pd2,
    float* __restrict__ ps3, float* __restrict__ pd3) {
  if (blockIdx.z == 3) {
    int gi = blockIdx.y * gridDim.x + blockIdx.x;
    if (gi >= 6) return;  // 6*256 >= KPAD
    int i = gi * 256 + threadIdx.x;
    if (i < KPAD) {
      int h = i / HS12, cin = i - h * HS12;
      bool live = (h < H1) && (cin < HID);
      int o = live ? (h * HID + cin) : 0;
      ps1[i] = live ? as1[o] : 0.f;
      pd1[i] = live ? ad1[o] : 0.f;
      ps2[i] = live ? as2[o] : 0.f;
      pd2[i] = live ? ad2[o] : 0.f;
    }
    if (i < LD3) {
      int h = i / HS3, cin = i - h * HS3;
      bool live = (h < H3) && (cin < NCLS);
      ps3[i] = live ? as3[h * NCLS + cin] : 0.f;
      pd3[i] = live ? ad3[h * NCLS + cin] : 0.f;
    }
    return;
  }
  const float* in; unsigned short* out;
  int K, Nm, kC, kS, Kp, nC, nS, Nmp;
  if (blockIdx.z == 0) {
    in = W1; out = o1; K = F_IN; Nm = HC1; kC = F_IN; kS = F_IN; Kp = F_IN;
    nC = HID; nS = HS12; Nmp = NL12;
  } else if (blockIdx.z == 1) {
    in = W2; out = o2; K = HC1; Nm = HC1; kC = HID; kS = HS12; Kp = KPAD;
    nC = HID; nS = HS12; Nmp = NL12;
  } else {
    in = W3; out = o3; K = HC1; Nm = H3 * NCLS; kC = HID; kS = HS12; Kp = KPAD;
    nC = NCLS; nS = HS3; Nmp = NL3;
  }
  int k0 = blockIdx.y * 64, n0 = blockIdx.x * 64;  // OUT coords
  if (k0 >= Kp || n0 >= Nmp) return;               // block-uniform exit
  __shared__ float tile[64][65];
  int c = threadIdx.x & 63, r = threadIdx.x >> 6;
  for (int rr = r; rr < 64; rr += 4) {
    int kp = k0 + rr;
    int np = n0 + c;
    float v = 0.f;
    if (kp < Kp && np < Nmp) {
      int ck = kp % kS, bk = kp / kS;
      int cn = np % nS, bn_ = np / nS;
      int ko = bk * kC + ck, no = bn_ * nC + cn;
      if (ck < kC && ko < K && cn < nC && no < Nm) v = in[(size_t)ko * Nm + no];
    }
    tile[rr][c] = v;
  }
  __syncthreads();
  for (int rr = r; rr < 64; rr += 4) {
    int np = n0 + rr, kp = k0 + c;
    if (np < Nmp && kp < Kp) out[(size_t)np * Kp + kp] = f2bf(tile[c][rr]);
  }
}

// ---------------------------------------------------------------------------
// MFMA GEMM: C = A @ Bt^T. 256x128 tile, BK=64, 512 threads (8 waves, 4x2).
// XCD-aware 1D grid swizzle (R11: FETCH 141->47 MB). mT % 8 == 0 required.
// blockIdx.y = split-K slice of span klen.
//   Cacc==null : bf16 store to Cbf (pad cols zeroed)
//   Cacc       : fp32 atomicAdd into Cacc (layer-3 split-K path)
// ---------------------------------------------------------------------------
#define BM 256
#define BN 128
#define BK 64

__global__ __launch_bounds__(512) void gemm_mfma(
    const unsigned short* __restrict__ A,   // [M][Kpad]
    const unsigned short* __restrict__ Bt,  // [Nmat][Kpad]
    unsigned short* __restrict__ Cbf,       // [M][ldc]
    int M, int Kpad, int Nmat, int ldc, int klen, int nT,
    float* __restrict__ Cacc) {
  __shared__ unsigned short As[BM * BK];  // 32 KB
  __shared__ unsigned short Bs[BN * BK];  // 16 KB
  int tid = threadIdx.x;
  int lane = tid & 63, wid = tid >> 6;     // 8 waves
  int wm = wid >> 1, wn = wid & 1;         // 4x2 wave grid, 64x64 per wave
  // XCD swizzle decode
  int bid = blockIdx.x;
  int slot = bid & 7, idx = bid >> 3;
  int nTi = idx % nT, mg = idx / nT;
  int bm = (slot + 8 * mg) * BM, bn = nTi * BN;
  int quad = lane >> 4, l16 = lane & 15;
  int kq = quad * 8;
  int koff = blockIdx.y * klen;

  // wave w stages A row-blocks {2w, 2w+1} (rows bm+32w+{0,16}) and B row-block w
  int ar0 = min(bm + 32 * wid + l16, M - 1);
  int ar1 = min(bm + 32 * wid + 16 + l16, M - 1);
  int br0 = min(bn + 16 * wid + l16, Nmat - 1);
  const unsigned short* gA0 = A + (size_t)ar0 * Kpad + kq;
  const unsigned short* gA1 = A + (size_t)ar1 * Kpad + kq;
  const unsigned short* gB0 = Bt + (size_t)br0 * Kpad + kq;
  unsigned short* lA = As + 4 * wid * 512;  // chunks 4w..4w+3 (rb*2+kh)
  unsigned short* lB = Bs + 2 * wid * 512;  // chunks 2w, 2w+1

  f32x4 acc[4][4] = {};

  for (int kt = koff; kt < koff + klen; kt += BK) {
    gl2lds16(gA0 + kt,      lA);
    gl2lds16(gA0 + kt + 32, lA + 512);
    gl2lds16(gA1 + kt,      lA + 1024);
    gl2lds16(gA1 + kt + 32, lA + 1536);
    gl2lds16(gB0 + kt,      lB);
    gl2lds16(gB0 + kt + 32, lB + 512);
    __syncthreads();
#pragma unroll
    for (int kh = 0; kh < 2; kh++) {
      bf16x8 af[4], bfr[4];
#pragma unroll
      for (int i = 0; i < 4; i++) {
        af[i]  = *(const bf16x8*)(As + ((wm * 4 + i) * 2 + kh) * 512 + lane * 8);
        bfr[i] = *(const bf16x8*)(Bs + ((wn * 4 + i) * 2 + kh) * 512 + lane * 8);
      }
#pragma unroll
      for (int i = 0; i < 4; i++)
#pragma unroll
        for (int j = 0; j < 4; j++)
          acc[i][j] = __builtin_amdgcn_mfma_f32_16x16x32_bf16(af[i], bfr[j], acc[i][j], 0, 0, 0);
    }
    __syncthreads();
  }

#pragma unroll
  for (int i = 0; i < 4; i++) {
    int rowb = bm + wm * 64 + i * 16 + quad * 4;
#pragma unroll
    for (int j = 0; j < 4; j++) {
      int col = bn + wn * 64 + j * 16 + l16;
      if (col < ldc) {
        bool live = col < Nmat;
        if (Cacc) {
#pragma unroll
          for (int r = 0; r < 4; r++) {
            int row = rowb + r;
            if (live && row < M) atomicAdd(&Cacc[(size_t)row * ldc + col], acc[i][j][r]);
          }
        } else {
#pragma unroll
          for (int r = 0; r < 4; r++) {
            int row = rowb + r;
            if (row < M) Cbf[(size_t)row * ldc + col] = live ? f2bf(acc[i][j][r]) : 0;
          }
        }
      }
    }
  }
}

// ---------------------------------------------------------------------------
// Attention coefficients (vectorized, head-padded). If Cacc != null (layer 3):
// read fp32 split-K accum, convert+store bf16 into hfeat, then dot.
// ---------------------------------------------------------------------------
__global__ void k_att(unsigned short* __restrict__ hfeat, int ldh,
                      const float* __restrict__ attp_s,
                      const float* __restrict__ attp_d,
                      float* __restrict__ asrc, float* __restrict__ adst,
                      int H, int HS,
                      const float* __restrict__ Cacc, int Nlive) {
  int n = blockIdx.x, t = threadIdx.x;
  __shared__ float s_ps[8], s_pd[8];
  if (t < 8) { s_ps[t] = 0.f; s_pd[t] = 0.f; }
  __syncthreads();
  int col0 = t * 8;
  if (col0 < ldh) {
    int hj = col0 / HS;
    float ps = 0.f, pd = 0.f;
    if (Cacc) {
      const float4* p = (const float4*)(Cacc + (size_t)n * ldh + col0);
      float4 f0 = p[0], f1 = p[1];
      float fv[8] = {f0.x, f0.y, f0.z, f0.w, f1.x, f1.y, f1.z, f1.w};
      u16x8 st;
#pragma unroll
      for (int j = 0; j < 8; j++) {
        bool live = (col0 + j) < Nlive;
        float v = live ? fv[j] : 0.f;
        st[j] = live ? f2bf(v) : 0;
        ps += v * attp_s[col0 + j];
        pd += v * attp_d[col0 + j];
      }
      *(u16x8*)(hfeat + (size_t)n * ldh + col0) = st;
    } else {
      u16x8 rv = *(const u16x8*)(hfeat + (size_t)n * ldh + col0);
#pragma unroll
      for (int j = 0; j < 8; j++) {
        float v = bf2f(rv[j]);
        ps += v * attp_s[col0 + j];
        pd += v * attp_d[col0 + j];
      }
    }
    atomicAdd(&s_ps[hj], ps);
    atomicAdd(&s_pd[hj], pd);
  }
  __syncthreads();
  if (t < H) {
    asrc[(size_t)n * H + t] = s_ps[t];
    adst[(size_t)n * H + t] = s_pd[t];
  }
}

// ---------------------------------------------------------------------------
// Aggregation with FUSED per-node softmax, single phase per node.
// blockDim = 192 (L1/L2: covers 1536 cols) or 64 (L3). Stats computed once by
// all threads (8 head-slots x blockDim/8 edge-slices, LDS merge). Gather uses
// a 4-edge in-flight pipeline.
// mode 0: +bias, ELU -> out_bf   mode 1: +bias +prevbf, ELU -> out_bf
// mode 2: raw -> LDS -> head-mean + b3 -> h3 (per-node row; k_pool reduces)
// ---------------------------------------------------------------------------
__global__ void k_agg(
    const unsigned short* __restrict__ hfeat, int ldh,
    const float* __restrict__ asrc,
    const float* __restrict__ adst,
    const int* __restrict__ csr_src,
    const int* __restrict__ offsets,
    const float* __restrict__ bias,
    const unsigned short* __restrict__ prevbf,
    unsigned short* __restrict__ out_bf,
    const float* __restrict__ b3,
    float* __restrict__ h3,
    int HS, int C, int H, int mode) {
  int n = blockIdx.x;
  int t = threadIdx.x;
  int nthr = blockDim.x;
  int s0 = offsets[n], s1 = offsets[n + 1];

  __shared__ float s_ad[8], s_pm[192], s_pl[192], s_mx[8], s_rinv[8];
  __shared__ int s_src[64];
  __shared__ float s_alpha[64 * 8];
  __shared__ float s_out[LD3];

  if (t < 8) s_ad[t] = (t < H) ? adst[(size_t)n * H + t] : 0.f;
  __syncthreads();

  // ---- online softmax stats: thread = (head t&7, edge-slice t>>3) ----
  int slices = nthr >> 3;
  int hh = t & 7, sl = t >> 3;
  float m = -1e30f, l = 0.f;
  if (hh < H) {
    float ad = s_ad[hh];
    for (int p = s0 + sl; p < s1; p += slices) {
      float v = asrc[csr_src[p] * H + hh] + ad;
      v = v > 0.f ? v : NEG_SLOPE * v;
      if (v > m) { l = l * expf(m - v) + 1.f; m = v; }
      else       { l += expf(v - m); }
    }
  }
  s_pm[t] = m; s_pl[t] = l;
  __syncthreads();
  if (t < 8) {
    float M2 = -1e30f, L2 = 0.f;
    for (int k = 0; k < slices; k++) {
      float mk = s_pm[t + 8 * k], lk = s_pl[t + 8 * k];
      if (mk > M2) { L2 = L2 * expf(M2 - mk) + lk; M2 = mk; }
      else         { L2 += lk * expf(mk - M2); }
    }
    s_mx[t] = M2;
    s_rinv[t] = 1.f / (L2 + EPSV);
  }
  __syncthreads();

  // ---- chunked gather (4-edge pipeline) ----
  int col0 = t * 8;
  bool active = col0 < ldh;
  int hj = active ? (col0 / HS) : 0;
  int cbase = col0 - hj * HS;
  float acc[8] = {};

  for (int base = s0; base < s1; base += 64) {
    int chunk = min(64, s1 - base);
    if (t < chunk) {
      int srcn = csr_src[base + t];
      s_src[t] = srcn;
      const float* ar = asrc + (size_t)srcn * H;
#pragma unroll
      for (int h = 0; h < 8; h++) {
        float a = 0.f;
        if (h < H) {
          float v = ar[h] + s_ad[h];
          v = v > 0.f ? v : NEG_SLOPE * v;
          a = expf(v - s_mx[h]) * s_rinv[h];
        }
        s_alpha[t * 8 + h] = a;
      }
    }
    __syncthreads();
    if (active) {
      const unsigned short* hb = hfeat + col0;
      u16x8 r[4] = {};
#pragma unroll
      for (int q = 0; q < 4; q++)
        if (q < chunk) r[q] = *(const u16x8*)(hb + (size_t)s_src[q] * ldh);
      int e = 0;
      for (; e + 4 <= chunk; e += 4) {
        u16x8 c0 = r[0], c1 = r[1], c2 = r[2], c3 = r[3];
#pragma unroll
        for (int q = 0; q < 4; q++)
          if (e + 4 + q < chunk) r[q] = *(const u16x8*)(hb + (size_t)s_src[e + 4 + q] * ldh);
        float a0 = s_alpha[e * 8 + hj];
        float a1 = s_alpha[(e + 1) * 8 + hj];
        float a2 = s_alpha[(e + 2) * 8 + hj];
        float a3 = s_alpha[(e + 3) * 8 + hj];
#pragma unroll
        for (int j = 0; j < 8; j++) {
          acc[j] += a0 * bf2f(c0[j]) + a1 * bf2f(c1[j]);
          acc[j] += a2 * bf2f(c2[j]) + a3 * bf2f(c3[j]);
        }
      }
      for (int q = 0; e + q < chunk; q++) {
        float a = s_alpha[(e + q) * 8 + hj];
#pragma unroll
        for (int j = 0; j < 8; j++) acc[j] += a * bf2f(r[q][j]);
      }
    }
    __syncthreads();
  }

  if (mode == 2) {
    if (active) {
#pragma unroll
      for (int j = 0; j < 8; j++) s_out[col0 + j] = acc[j];
    }
    __syncthreads();
    if (t < NCLS)
      h3[(size_t)n * NCLS + t] =
          (s_out[t] + s_out[HS + t] + s_out[2 * HS + t]) * (1.f / 3.f) + b3[t];
    return;
  }

  if (!active) return;
#pragma unroll
  for (int j = 0; j < 8; j++) {
    int cin = cbase + j;
    bool live = (hj < H) && (cin < C);
    float v = 0.f;
    if (live) {
      v = acc[j] + bias[hj * C + cin];
      if (mode == 1) v += bf2f(prevbf[(size_t)n * ldh + col0 + j]);
      v = v > 0.f ? v : (expf(v) - 1.f);  // ELU
    }
    out_bf[(size_t)n * ldh + col0 + j] = live ? f2bf(v) : 0;
  }
}

// Pooled column sums: per-block strided partials, ONE atomic per (block,col).
__global__ void k_pool(const float* __restrict__ h3, float* __restrict__ pooled,
                       int N) {
  int col = threadIdx.x;  // blockDim = (64,4)
  if (col >= NCLS) return;
  int row = blockIdx.x * 4 + threadIdx.y;
  int stride = gridDim.x * 4;
  float acc = 0.f;
  for (int r = row; r < N; r += stride) acc += h3[(size_t)r * NCLS + col];
  atomicAdd(&pooled[col], acc);
}

// pooled -> out[0:40], log_softmax(pooled) -> out[40:80]
__global__ __launch_bounds__(64) void k_final(const float* __restrict__ pooled,
                                              float* __restrict__ out) {
  int t = threadIdx.x;
  float v = (t < NCLS) ? pooled[t] : -INFINITY;
  float m = v;
  for (int o = 32; o > 0; o >>= 1) m = fmaxf(m, __shfl_xor(m, o));
  float ex = (t < NCLS) ? expf(v - m) : 0.f;
  float s = ex;
  for (int o = 32; o > 0; o >>= 1) s += __shfl_xor(s, o);
  float lse = m + logf(s);
  if (t < NCLS) {
    out[t] = v;
    out[NCLS + t] = v - lse;
  }
}

// ---------------------------------------------------------------------------
extern "C" void kernel_launch(void* const* d_in, const int* in_sizes, int n_in,
                              void* d_out, int out_size, void* d_ws, size_t ws_size,
                              hipStream_t stream) {
  const float* x   = (const float*)d_in[0];
  const int*   ei  = (const int*)d_in[1];
  const float* W1  = (const float*)d_in[2];
  const float* as1 = (const float*)d_in[3];
  const float* ad1 = (const float*)d_in[4];
  const float* b1  = (const float*)d_in[5];
  const float* W2  = (const float*)d_in[6];
  const float* as2 = (const float*)d_in[7];
  const float* ad2 = (const float*)d_in[8];
  const float* b2  = (const float*)d_in[9];
  const float* W3  = (const float*)d_in[10];
  const float* as3 = (const float*)d_in[11];
  const float* ad3 = (const float*)d_in[12];
  const float* b3  = (const float*)d_in[13];
  float* out = (float*)d_out;

  const int N = NN;
  const int E0 = in_sizes[1] / 2;   // 80000
  const int Etot = E0 + N;          // 90000
  const int mT = (N + BM - 1) / BM; // 40 (divisible by 8 -> swizzle valid)

  // workspace layout — pooled/Cacc/counts contiguous => ONE memset
  float* f = (float*)d_ws;
  float* asrc   = f;                               // [N,5]
  float* adst   = asrc + (size_t)N * H1;           // [N,5]
  float* pooled = adst + (size_t)N * H1;           // [64]   <- zero region start
  float* Cacc   = pooled + 64;                     // [N,160]
  int* counts  = (int*)(Cacc + (size_t)N * LD3);   // [N]    <- zero region end
  float* h3     = (float*)(counts + N);            // [N,40]
  float* attps1 = h3 + (size_t)N * NCLS;           // [1536] x6
  float* attpd1 = attps1 + KPAD;
  float* attps2 = attpd1 + KPAD;
  float* attpd2 = attps2 + KPAD;
  float* attps3 = attpd2 + KPAD;                   // [160]
  float* attpd3 = attps3 + LD3;
  int* offsets = (int*)(attpd3 + LD3);             // [N+1]
  int* cursor  = offsets + N + 1;
  int* csr_src = cursor + N;
  uintptr_t pp = (uintptr_t)(csr_src + Etot);
  pp = (pp + 15) & ~(uintptr_t)15;
  unsigned short* hfbf  = (unsigned short*)pp;        // [N][KPAD] GEMM output
  unsigned short* abf   = hfbf + (size_t)N * KPAD;    // [N][KPAD] activations
  unsigned short* btbf1 = abf + (size_t)N * KPAD;     // [NL12][F_IN]
  unsigned short* btbf2 = btbf1 + (size_t)NL12 * F_IN; // [NL12][KPAD]
  unsigned short* btbf3 = btbf2 + (size_t)NL12 * KPAD; // [NL3][KPAD]

  hipMemsetAsync(pooled, 0, (64 + (size_t)N * LD3) * sizeof(float) + N * sizeof(int),
                 stream);

  // CSR build + preprocessing (weights transpose + att pad), input-only
  k_count<<<(Etot + 255) / 256, 256, 0, stream>>>(ei, counts, E0, Etot);
  k_scan<<<1, 256, 0, stream>>>(counts, offsets, cursor, N, Etot);
  k_scatter<<<(Etot + 255) / 256, 256, 0, stream>>>(ei, cursor, csr_src, E0, Etot);
  {
    dim3 tg((NL12 + 63) / 64, (KPAD + 63) / 64, 4);
    k_prep<<<tg, 256, 0, stream>>>(W1, W2, W3, btbf1, btbf2, btbf3,
                                   as1, ad1, as2, ad2, as3, ad3,
                                   attps1, attpd1, attps2, attpd2, attps3, attpd3);
  }

  // ---- Layer 1 (K=128, N=1520 padded) ----
  {
    k_cvt<<<((long long)N * F_IN + 255) / 256, 256, 0, stream>>>(x, abf, N, F_IN, F_IN);
    int nT = (NL12 + BN - 1) / BN;  // 12
    gemm_mfma<<<dim3(nT * mT, 1), 512, 0, stream>>>(abf, btbf1, hfbf, N, F_IN, NL12,
                                                    KPAD, F_IN, nT, nullptr);
    k_att<<<N, 192, 0, stream>>>(hfbf, KPAD, attps1, attpd1, asrc, adst, H1, HS12,
                                 nullptr, 0);
    k_agg<<<N, 192, 0, stream>>>(hfbf, KPAD, asrc, adst, csr_src, offsets,
                                 b1, nullptr, abf, nullptr, nullptr,
                                 HS12, HID, H1, 0);
  }

  // ---- Layer 2 (K=1536); residual read from abf (bf16), output aliases abf ----
  {
    int nT = (NL12 + BN - 1) / BN;  // 12
    gemm_mfma<<<dim3(nT * mT, 1), 512, 0, stream>>>(abf, btbf2, hfbf, N, KPAD, NL12,
                                                    KPAD, KPAD, nT, nullptr);
    k_att<<<N, 192, 0, stream>>>(hfbf, KPAD, attps2, attpd2, asrc, adst, H1, HS12,
                                 nullptr, 0);
    k_agg<<<N, 192, 0, stream>>>(hfbf, KPAD, asrc, adst, csr_src, offsets,
                                 b2, abf, abf, nullptr, nullptr,
                                 HS12, HID, H1, 1);
  }

  // ---- Layer 3 (K=1536, N=144, ldc=160), split-K=4 atomic; cvt fused in k_att ----
  {
    int nT = (LD3 + BN - 1) / BN;   // 2
    gemm_mfma<<<dim3(nT * mT, 4), 512, 0, stream>>>(abf, btbf3, nullptr, N, KPAD, NL3,
                                                    LD3, KPAD / 4, nT, Cacc);
    k_att<<<N, 64, 0, stream>>>(hfbf, LD3, attps3, attpd3, asrc, adst, H3, HS3,
                                Cacc, NL3);
    k_agg<<<N, 64, 0, stream>>>(hfbf, LD3, asrc, adst, csr_src, offsets,
                                nullptr, nullptr, nullptr, b3, h3,
                                HS3, NCLS, H3, 2);
  }

  // ---- Pool + log_softmax
  k_pool<<<64, dim3(64, 4), 0, stream>>>(h3, pooled, N);
  k_final<<<1, 64, 0, stream>>>(pooled, out);
}

// Round 19
// 515.965 us; speedup vs baseline: 1.1890x; 1.1890x over previous
//
#include <hip/hip_runtime.h>
#include <hip/hip_bf16.h>
#include <math.h>

// Problem constants (fixed by the reference)
#define NN       10000      // nodes
#define F_IN     128
#define HID      300
#define H1       5
#define H3       3
#define NCLS     40
#define HC1      (H1*HID)   // 1500
#define KPAD     1536       // padded K / activation row stride (bf16)
#define HS12     304        // head col stride, layers 1-2 (300+4, mult of 16)
#define NL12     1520       // live padded cols layers 1-2 (5*304)
#define HS3      48         // head col stride, layer 3 (40+8, mult of 16)
#define NL3      144        // live padded cols layer 3 (3*48)
#define LD3      160        // layer-3 row stride
#define NEG_SLOPE 0.2f
#define EPSV     1e-16f

typedef __attribute__((ext_vector_type(8))) short bf16x8;
typedef __attribute__((ext_vector_type(8))) unsigned short u16x8;
typedef __attribute__((ext_vector_type(4))) float f32x4;

__device__ inline unsigned short f2bf(float f) {
  unsigned int u = __builtin_bit_cast(unsigned int, f);
  unsigned int r = (u + 0x7FFFu + ((u >> 16) & 1u)) >> 16;   // RNE
  return (unsigned short)r;
}
__device__ inline float bf2f(unsigned short s) {
  unsigned int u = ((unsigned int)s) << 16;
  return __builtin_bit_cast(float, u);
}

// async 16B/lane global->LDS (lds dest = wave-uniform base + lane*16)
__device__ __forceinline__ void gl2lds16(const unsigned short* g, unsigned short* l) {
  __builtin_amdgcn_global_load_lds(
      (const __attribute__((address_space(1))) unsigned int*)(const void*)g,
      (__attribute__((address_space(3))) unsigned int*)(void*)l, 16, 0, 0);
}

// ---------------------------------------------------------------------------
// CSR build
// ---------------------------------------------------------------------------
__global__ void k_count(const int* __restrict__ ei, int* __restrict__ counts,
                        int E0, int Etot) {
  int e = blockIdx.x * 256 + threadIdx.x;
  if (e >= Etot) return;
  int dst = (e < E0) ? ei[E0 + e] : (e - E0);
  atomicAdd(&counts[dst], 1);
}

__global__ __launch_bounds__(256) void k_scan(const int* __restrict__ counts,
                                              int* __restrict__ offsets,
                                              int* __restrict__ cursor,
                                              int N, int Etot) {
  __shared__ int sh[256];
  const int CH = 40;  // 256*40 = 10240 >= N
  int t = threadIdx.x;
  int base = t * CH;
  int s = 0;
  for (int i = 0; i < CH; i++) {
    int idx = base + i;
    if (idx < N) s += counts[idx];
  }
  sh[t] = s;
  __syncthreads();
  for (int d = 1; d < 256; d <<= 1) {
    int v = (t >= d) ? sh[t - d] : 0;
    __syncthreads();
    sh[t] += v;
    __syncthreads();
  }
  int run = sh[t] - s;  // exclusive prefix
  for (int i = 0; i < CH; i++) {
    int idx = base + i;
    if (idx < N) {
      offsets[idx] = run;
      cursor[idx] = run;
      run += counts[idx];
    }
  }
  if (t == 0) offsets[N] = Etot;
}

__global__ void k_scatter(const int* __restrict__ ei, int* __restrict__ cursor,
                          int* __restrict__ csr_src, int E0, int Etot) {
  int e = blockIdx.x * 256 + threadIdx.x;
  if (e >= Etot) return;
  int src, dst;
  if (e < E0) { src = ei[e]; dst = ei[E0 + e]; }
  else        { src = dst = e - E0; }
  int pos = atomicAdd(&cursor[dst], 1);
  csr_src[pos] = src;
}

// ---------------------------------------------------------------------------
// fp32 -> bf16 cast (x input)
// ---------------------------------------------------------------------------
__global__ void k_cvt(const float* __restrict__ in, unsigned short* __restrict__ out,
                      int R, int C, int Cpad) {
  long long idx = (long long)blockIdx.x * 256 + threadIdx.x;
  if (idx >= (long long)R * Cpad) return;
  int r = (int)(idx / Cpad), c = (int)(idx - (long long)r * Cpad);
  out[idx] = (c < C) ? f2bf(in[(size_t)r * C + c]) : 0;
}

// ---------------------------------------------------------------------------
// Preprocessing mega-kernel: z<3 = weight transpose jobs (head-pad remap both
// dims); z==3 = att-vector padding for all 3 layers.
// ---------------------------------------------------------------------------
__global__ __launch_bounds__(256) void k_prep(
    const float* __restrict__ W1, const float* __restrict__ W2,
    const float* __restrict__ W3,
    unsigned short* __restrict__ o1, unsigned short* __restrict__ o2,
    unsigned short* __restrict__ o3,
    const float* __restrict__ as1, const float* __restrict__ ad1,
    const float* __restrict__ as2, const float* __restrict__ ad2,
    const float* __restrict__ as3, const float* __restrict__ ad3,
    float* __restrict__ ps1, float* __restrict__ pd1,
    float* __restrict__ ps2, float* __restrict__ pd2,
    float* __restrict__ ps3, float* __restrict__ pd3) {
  if (blockIdx.z == 3) {
    int gi = blockIdx.y * gridDim.x + blockIdx.x;
    if (gi >= 6) return;  // 6*256 >= KPAD
    int i = gi * 256 + threadIdx.x;
    if (i < KPAD) {
      int h = i / HS12, cin = i - h * HS12;
      bool live = (h < H1) && (cin < HID);
      int o = live ? (h * HID + cin) : 0;
      ps1[i] = live ? as1[o] : 0.f;
      pd1[i] = live ? ad1[o] : 0.f;
      ps2[i] = live ? as2[o] : 0.f;
      pd2[i] = live ? ad2[o] : 0.f;
    }
    if (i < LD3) {
      int h = i / HS3, cin = i - h * HS3;
      bool live = (h < H3) && (cin < NCLS);
      ps3[i] = live ? as3[h * NCLS + cin] : 0.f;
      pd3[i] = live ? ad3[h * NCLS + cin] : 0.f;
    }
    return;
  }
  const float* in; unsigned short* out;
  int K, Nm, kC, kS, Kp, nC, nS, Nmp;
  if (blockIdx.z == 0) {
    in = W1; out = o1; K = F_IN; Nm = HC1; kC = F_IN; kS = F_IN; Kp = F_IN;
    nC = HID; nS = HS12; Nmp = NL12;
  } else if (blockIdx.z == 1) {
    in = W2; out = o2; K = HC1; Nm = HC1; kC = HID; kS = HS12; Kp = KPAD;
    nC = HID; nS = HS12; Nmp = NL12;
  } else {
    in = W3; out = o3; K = HC1; Nm = H3 * NCLS; kC = HID; kS = HS12; Kp = KPAD;
    nC = NCLS; nS = HS3; Nmp = NL3;
  }
  int k0 = blockIdx.y * 64, n0 = blockIdx.x * 64;  // OUT coords
  if (k0 >= Kp || n0 >= Nmp) return;               // block-uniform exit
  __shared__ float tile[64][65];
  int c = threadIdx.x & 63, r = threadIdx.x >> 6;
  for (int rr = r; rr < 64; rr += 4) {
    int kp = k0 + rr;
    int np = n0 + c;
    float v = 0.f;
    if (kp < Kp && np < Nmp) {
      int ck = kp % kS, bk = kp / kS;
      int cn = np % nS, bn_ = np / nS;
      int ko = bk * kC + ck, no = bn_ * nC + cn;
      if (ck < kC && ko < K && cn < nC && no < Nm) v = in[(size_t)ko * Nm + no];
    }
    tile[rr][c] = v;
  }
  __syncthreads();
  for (int rr = r; rr < 64; rr += 4) {
    int np = n0 + rr, kp = k0 + c;
    if (np < Nmp && kp < Kp) out[(size_t)np * Kp + kp] = f2bf(tile[c][rr]);
  }
}

// ---------------------------------------------------------------------------
// MFMA GEMM: C = A @ Bt^T. 256x128 tile, BK=64, 512 threads (8 waves, 4x2).
// XCD-aware 1D grid swizzle (R11: FETCH 141->47 MB). mT % 8 == 0 required.
// blockIdx.y = split-K slice of span klen.
//   Cacc==null : bf16 store to Cbf (pad cols zeroed)
//   Cacc       : fp32 atomicAdd into Cacc (layer-3 split-K path)
// ---------------------------------------------------------------------------
#define BM 256
#define BN 128
#define BK 64

__global__ __launch_bounds__(512) void gemm_mfma(
    const unsigned short* __restrict__ A,   // [M][Kpad]
    const unsigned short* __restrict__ Bt,  // [Nmat][Kpad]
    unsigned short* __restrict__ Cbf,       // [M][ldc]
    int M, int Kpad, int Nmat, int ldc, int klen, int nT,
    float* __restrict__ Cacc) {
  __shared__ unsigned short As[BM * BK];  // 32 KB
  __shared__ unsigned short Bs[BN * BK];  // 16 KB
  int tid = threadIdx.x;
  int lane = tid & 63, wid = tid >> 6;     // 8 waves
  int wm = wid >> 1, wn = wid & 1;         // 4x2 wave grid, 64x64 per wave
  // XCD swizzle decode
  int bid = blockIdx.x;
  int slot = bid & 7, idx = bid >> 3;
  int nTi = idx % nT, mg = idx / nT;
  int bm = (slot + 8 * mg) * BM, bn = nTi * BN;
  int quad = lane >> 4, l16 = lane & 15;
  int kq = quad * 8;
  int koff = blockIdx.y * klen;

  // wave w stages A row-blocks {2w, 2w+1} (rows bm+32w+{0,16}) and B row-block w
  int ar0 = min(bm + 32 * wid + l16, M - 1);
  int ar1 = min(bm + 32 * wid + 16 + l16, M - 1);
  int br0 = min(bn + 16 * wid + l16, Nmat - 1);
  const unsigned short* gA0 = A + (size_t)ar0 * Kpad + kq;
  const unsigned short* gA1 = A + (size_t)ar1 * Kpad + kq;
  const unsigned short* gB0 = Bt + (size_t)br0 * Kpad + kq;
  unsigned short* lA = As + 4 * wid * 512;  // chunks 4w..4w+3 (rb*2+kh)
  unsigned short* lB = Bs + 2 * wid * 512;  // chunks 2w, 2w+1

  f32x4 acc[4][4] = {};

  for (int kt = koff; kt < koff + klen; kt += BK) {
    gl2lds16(gA0 + kt,      lA);
    gl2lds16(gA0 + kt + 32, lA + 512);
    gl2lds16(gA1 + kt,      lA + 1024);
    gl2lds16(gA1 + kt + 32, lA + 1536);
    gl2lds16(gB0 + kt,      lB);
    gl2lds16(gB0 + kt + 32, lB + 512);
    __syncthreads();
#pragma unroll
    for (int kh = 0; kh < 2; kh++) {
      bf16x8 af[4], bfr[4];
#pragma unroll
      for (int i = 0; i < 4; i++) {
        af[i]  = *(const bf16x8*)(As + ((wm * 4 + i) * 2 + kh) * 512 + lane * 8);
        bfr[i] = *(const bf16x8*)(Bs + ((wn * 4 + i) * 2 + kh) * 512 + lane * 8);
      }
#pragma unroll
      for (int i = 0; i < 4; i++)
#pragma unroll
        for (int j = 0; j < 4; j++)
          acc[i][j] = __builtin_amdgcn_mfma_f32_16x16x32_bf16(af[i], bfr[j], acc[i][j], 0, 0, 0);
    }
    __syncthreads();
  }

#pragma unroll
  for (int i = 0; i < 4; i++) {
    int rowb = bm + wm * 64 + i * 16 + quad * 4;
#pragma unroll
    for (int j = 0; j < 4; j++) {
      int col = bn + wn * 64 + j * 16 + l16;
      if (col < ldc) {
        bool live = col < Nmat;
        if (Cacc) {
#pragma unroll
          for (int r = 0; r < 4; r++) {
            int row = rowb + r;
            if (live && row < M) atomicAdd(&Cacc[(size_t)row * ldc + col], acc[i][j][r]);
          }
        } else {
#pragma unroll
          for (int r = 0; r < 4; r++) {
            int row = rowb + r;
            if (row < M) Cbf[(size_t)row * ldc + col] = live ? f2bf(acc[i][j][r]) : 0;
          }
        }
      }
    }
  }
}

// ---------------------------------------------------------------------------
// Attention coefficients (vectorized, head-padded). If Cacc != null (layer 3):
// read fp32 split-K accum, convert+store bf16 into hfeat, then dot.
// ---------------------------------------------------------------------------
__global__ void k_att(unsigned short* __restrict__ hfeat, int ldh,
                      const float* __restrict__ attp_s,
                      const float* __restrict__ attp_d,
                      float* __restrict__ asrc, float* __restrict__ adst,
                      int H, int HS,
                      const float* __restrict__ Cacc, int Nlive) {
  int n = blockIdx.x, t = threadIdx.x;
  __shared__ float s_ps[8], s_pd[8];
  if (t < 8) { s_ps[t] = 0.f; s_pd[t] = 0.f; }
  __syncthreads();
  int col0 = t * 8;
  if (col0 < ldh) {
    int hj = col0 / HS;
    float ps = 0.f, pd = 0.f;
    if (Cacc) {
      const float4* p = (const float4*)(Cacc + (size_t)n * ldh + col0);
      float4 f0 = p[0], f1 = p[1];
      float fv[8] = {f0.x, f0.y, f0.z, f0.w, f1.x, f1.y, f1.z, f1.w};
      u16x8 st;
#pragma unroll
      for (int j = 0; j < 8; j++) {
        bool live = (col0 + j) < Nlive;
        float v = live ? fv[j] : 0.f;
        st[j] = live ? f2bf(v) : 0;
        ps += v * attp_s[col0 + j];
        pd += v * attp_d[col0 + j];
      }
      *(u16x8*)(hfeat + (size_t)n * ldh + col0) = st;
    } else {
      u16x8 rv = *(const u16x8*)(hfeat + (size_t)n * ldh + col0);
#pragma unroll
      for (int j = 0; j < 8; j++) {
        float v = bf2f(rv[j]);
        ps += v * attp_s[col0 + j];
        pd += v * attp_d[col0 + j];
      }
    }
    atomicAdd(&s_ps[hj], ps);
    atomicAdd(&s_pd[hj], pd);
  }
  __syncthreads();
  if (t < H) {
    asrc[(size_t)n * H + t] = s_ps[t];
    adst[(size_t)n * H + t] = s_pd[t];
  }
}

// ---------------------------------------------------------------------------
// Aggregation with FUSED per-node softmax, column-phased (R17 structure —
// phases give cross-block L2/L3 slice locality; single-phase measured 145MB
// FETCH vs phased ~45MB, R18). Block (n, phase) = 512 cols; 64 threads.
// Gather: 2-edge depth-2 pipeline. Alpha fill: one thread per edge.
// mode 0: +bias, ELU -> out_bf   mode 1: +bias +prevbf, ELU -> out_bf
// mode 2: raw -> LDS -> head-mean + b3 -> h3 (per-node row; k_pool reduces)
// ---------------------------------------------------------------------------
__global__ __launch_bounds__(64) void k_agg(
    const unsigned short* __restrict__ hfeat, int ldh,
    const float* __restrict__ asrc,
    const float* __restrict__ adst,
    const int* __restrict__ csr_src,
    const int* __restrict__ offsets,
    const float* __restrict__ bias,
    const unsigned short* __restrict__ prevbf,
    unsigned short* __restrict__ out_bf,
    const float* __restrict__ b3,
    float* __restrict__ h3,
    int HS, int C, int H, int mode) {
  int n = blockIdx.x;
  int t = threadIdx.x;
  int s0 = offsets[n], s1 = offsets[n + 1];

  __shared__ float s_ad[8], s_pm[64], s_pl[64], s_mx[8], s_rinv[8];
  __shared__ int s_src[64];
  __shared__ float s_alpha[64 * 8];
  __shared__ float s_out[LD3];

  if (t < 8) s_ad[t] = (t < H) ? adst[(size_t)n * H + t] : 0.f;
  __syncthreads();

  // ---- online softmax stats: thread = (head t&7, edge-slice t>>3) ----
  int hh = t & 7, sl = t >> 3;
  float m = -1e30f, l = 0.f;
  if (hh < H) {
    float ad = s_ad[hh];
    for (int p = s0 + sl; p < s1; p += 8) {
      float v = asrc[csr_src[p] * H + hh] + ad;
      v = v > 0.f ? v : NEG_SLOPE * v;
      if (v > m) { l = l * expf(m - v) + 1.f; m = v; }
      else       { l += expf(v - m); }
    }
  }
  s_pm[t] = m; s_pl[t] = l;
  __syncthreads();
  if (t < 8) {
    float M2 = -1e30f, L2 = 0.f;
    for (int k = 0; k < 8; k++) {
      float mk = s_pm[t + 8 * k], lk = s_pl[t + 8 * k];
      if (mk > M2) { L2 = L2 * expf(M2 - mk) + lk; M2 = mk; }
      else         { L2 += lk * expf(mk - M2); }
    }
    s_mx[t] = M2;
    s_rinv[t] = 1.f / (L2 + EPSV);
  }
  __syncthreads();

  // ---- chunked gather (2-edge depth-2 pipeline) ----
  int col0 = blockIdx.y * 512 + t * 8;
  bool active = col0 < ldh;
  int hj = active ? (col0 / HS) : 0;
  int cbase = col0 - hj * HS;
  float acc[8] = {};

  for (int base = s0; base < s1; base += 64) {
    int chunk = min(64, s1 - base);
    if (t < chunk) {
      int srcn = csr_src[base + t];
      s_src[t] = srcn;
      const float* ar = asrc + (size_t)srcn * H;
#pragma unroll
      for (int h = 0; h < 8; h++) {
        float a = 0.f;
        if (h < H) {
          float v = ar[h] + s_ad[h];
          v = v > 0.f ? v : NEG_SLOPE * v;
          a = expf(v - s_mx[h]) * s_rinv[h];
        }
        s_alpha[t * 8 + h] = a;
      }
    }
    __syncthreads();
    if (active) {
      const unsigned short* hb = hfeat + col0;
      u16x8 rv0 = {}, rv1 = {};
      if (chunk > 0) rv0 = *(const u16x8*)(hb + (size_t)s_src[0] * ldh);
      if (chunk > 1) rv1 = *(const u16x8*)(hb + (size_t)s_src[1] * ldh);
      int e = 0;
      for (; e + 2 <= chunk; e += 2) {
        u16x8 c0 = rv0, c1 = rv1;
        if (e + 2 < chunk) rv0 = *(const u16x8*)(hb + (size_t)s_src[e + 2] * ldh);
        if (e + 3 < chunk) rv1 = *(const u16x8*)(hb + (size_t)s_src[e + 3] * ldh);
        float a0 = s_alpha[e * 8 + hj];
        float a1 = s_alpha[(e + 1) * 8 + hj];
#pragma unroll
        for (int j = 0; j < 8; j++) {
          acc[j] += a0 * bf2f(c0[j]);
          acc[j] += a1 * bf2f(c1[j]);
        }
      }
      if (e < chunk) {
        float a0 = s_alpha[e * 8 + hj];
#pragma unroll
        for (int j = 0; j < 8; j++) acc[j] += a0 * bf2f(rv0[j]);
      }
    }
    __syncthreads();
  }

  if (mode == 2) {
    if (active) {
#pragma unroll
      for (int j = 0; j < 8; j++) s_out[col0 + j] = acc[j];
    }
    __syncthreads();
    if (t < NCLS)
      h3[(size_t)n * NCLS + t] =
          (s_out[t] + s_out[HS + t] + s_out[2 * HS + t]) * (1.f / 3.f) + b3[t];
    return;
  }

  if (!active) return;
#pragma unroll
  for (int j = 0; j < 8; j++) {
    int cin = cbase + j;
    bool live = (hj < H) && (cin < C);
    float v = 0.f;
    if (live) {
      v = acc[j] + bias[hj * C + cin];
      if (mode == 1) v += bf2f(prevbf[(size_t)n * ldh + col0 + j]);
      v = v > 0.f ? v : (expf(v) - 1.f);  // ELU
    }
    out_bf[(size_t)n * ldh + col0 + j] = live ? f2bf(v) : 0;
  }
}

// Pooled column sums: per-block strided partials, ONE atomic per (block,col).
__global__ void k_pool(const float* __restrict__ h3, float* __restrict__ pooled,
                       int N) {
  int col = threadIdx.x;  // blockDim = (64,4)
  if (col >= NCLS) return;
  int row = blockIdx.x * 4 + threadIdx.y;
  int stride = gridDim.x * 4;
  float acc = 0.f;
  for (int r = row; r < N; r += stride) acc += h3[(size_t)r * NCLS + col];
  atomicAdd(&pooled[col], acc);
}

// pooled -> out[0:40], log_softmax(pooled) -> out[40:80]
__global__ __launch_bounds__(64) void k_final(const float* __restrict__ pooled,
                                              float* __restrict__ out) {
  int t = threadIdx.x;
  float v = (t < NCLS) ? pooled[t] : -INFINITY;
  float m = v;
  for (int o = 32; o > 0; o >>= 1) m = fmaxf(m, __shfl_xor(m, o));
  float ex = (t < NCLS) ? expf(v - m) : 0.f;
  float s = ex;
  for (int o = 32; o > 0; o >>= 1) s += __shfl_xor(s, o);
  float lse = m + logf(s);
  if (t < NCLS) {
    out[t] = v;
    out[NCLS + t] = v - lse;
  }
}

// ---------------------------------------------------------------------------
extern "C" void kernel_launch(void* const* d_in, const int* in_sizes, int n_in,
                              void* d_out, int out_size, void* d_ws, size_t ws_size,
                              hipStream_t stream) {
  const float* x   = (const float*)d_in[0];
  const int*   ei  = (const int*)d_in[1];
  const float* W1  = (const float*)d_in[2];
  const float* as1 = (const float*)d_in[3];
  const float* ad1 = (const float*)d_in[4];
  const float* b1  = (const float*)d_in[5];
  const float* W2  = (const float*)d_in[6];
  const float* as2 = (const float*)d_in[7];
  const float* ad2 = (const float*)d_in[8];
  const float* b2  = (const float*)d_in[9];
  const float* W3  = (const float*)d_in[10];
  const float* as3 = (const float*)d_in[11];
  const float* ad3 = (const float*)d_in[12];
  const float* b3  = (const float*)d_in[13];
  float* out = (float*)d_out;

  const int N = NN;
  const int E0 = in_sizes[1] / 2;   // 80000
  const int Etot = E0 + N;          // 90000
  const int mT = (N + BM - 1) / BM; // 40 (divisible by 8 -> swizzle valid)

  // workspace layout — pooled/Cacc/counts contiguous => ONE memset
  float* f = (float*)d_ws;
  float* asrc   = f;                               // [N,5]
  float* adst   = asrc + (size_t)N * H1;           // [N,5]
  float* pooled = adst + (size_t)N * H1;           // [64]   <- zero region start
  float* Cacc   = pooled + 64;                     // [N,160]
  int* counts  = (int*)(Cacc + (size_t)N * LD3);   // [N]    <- zero region end
  float* h3     = (float*)(counts + N);            // [N,40]
  float* attps1 = h3 + (size_t)N * NCLS;           // [1536] x6
  float* attpd1 = attps1 + KPAD;
  float* attps2 = attpd1 + KPAD;
  float* attpd2 = attps2 + KPAD;
  float* attps3 = attpd2 + KPAD;                   // [160]
  float* attpd3 = attps3 + LD3;
  int* offsets = (int*)(attpd3 + LD3);             // [N+1]
  int* cursor  = offsets + N + 1;
  int* csr_src = cursor + N;
  uintptr_t pp = (uintptr_t)(csr_src + Etot);
  pp = (pp + 15) & ~(uintptr_t)15;
  unsigned short* hfbf  = (unsigned short*)pp;        // [N][KPAD] GEMM output
  unsigned short* abf   = hfbf + (size_t)N * KPAD;    // [N][KPAD] activations
  unsigned short* btbf1 = abf + (size_t)N * KPAD;     // [NL12][F_IN]
  unsigned short* btbf2 = btbf1 + (size_t)NL12 * F_IN; // [NL12][KPAD]
  unsigned short* btbf3 = btbf2 + (size_t)NL12 * KPAD; // [NL3][KPAD]

  hipMemsetAsync(pooled, 0, (64 + (size_t)N * LD3) * sizeof(float) + N * sizeof(int),
                 stream);

  // CSR build + preprocessing (weights transpose + att pad), input-only
  k_count<<<(Etot + 255) / 256, 256, 0, stream>>>(ei, counts, E0, Etot);
  k_scan<<<1, 256, 0, stream>>>(counts, offsets, cursor, N, Etot);
  k_scatter<<<(Etot + 255) / 256, 256, 0, stream>>>(ei, cursor, csr_src, E0, Etot);
  {
    dim3 tg((NL12 + 63) / 64, (KPAD + 63) / 64, 4);
    k_prep<<<tg, 256, 0, stream>>>(W1, W2, W3, btbf1, btbf2, btbf3,
                                   as1, ad1, as2, ad2, as3, ad3,
                                   attps1, attpd1, attps2, attpd2, attps3, attpd3);
  }

  // ---- Layer 1 (K=128, N=1520 padded) ----
  {
    k_cvt<<<((long long)N * F_IN + 255) / 256, 256, 0, stream>>>(x, abf, N, F_IN, F_IN);
    int nT = (NL12 + BN - 1) / BN;  // 12
    gemm_mfma<<<dim3(nT * mT, 1), 512, 0, stream>>>(abf, btbf1, hfbf, N, F_IN, NL12,
                                                    KPAD, F_IN, nT, nullptr);
    k_att<<<N, 192, 0, stream>>>(hfbf, KPAD, attps1, attpd1, asrc, adst, H1, HS12,
                                 nullptr, 0);
    k_agg<<<dim3(N, 3), 64, 0, stream>>>(hfbf, KPAD, asrc, adst, csr_src, offsets,
                                         b1, nullptr, abf, nullptr, nullptr,
                                         HS12, HID, H1, 0);
  }

  // ---- Layer 2 (K=1536); residual read from abf (bf16), output aliases abf ----
  {
    int nT = (NL12 + BN - 1) / BN;  // 12
    gemm_mfma<<<dim3(nT * mT, 1), 512, 0, stream>>>(abf, btbf2, hfbf, N, KPAD, NL12,
                                                    KPAD, KPAD, nT, nullptr);
    k_att<<<N, 192, 0, stream>>>(hfbf, KPAD, attps2, attpd2, asrc, adst, H1, HS12,
                                 nullptr, 0);
    k_agg<<<dim3(N, 3), 64, 0, stream>>>(hfbf, KPAD, asrc, adst, csr_src, offsets,
                                         b2, abf, abf, nullptr, nullptr,
                                         HS12, HID, H1, 1);
  }

  // ---- Layer 3 (K=1536, N=144, ldc=160), split-K=4 atomic; cvt fused in k_att ----
  {
    int nT = (LD3 + BN - 1) / BN;   // 2
    gemm_mfma<<<dim3(nT * mT, 4), 512, 0, stream>>>(abf, btbf3, nullptr, N, KPAD, NL3,
                                                    LD3, KPAD / 4, nT, Cacc);
    k_att<<<N, 64, 0, stream>>>(hfbf, LD3, attps3, attpd3, asrc, adst, H3, HS3,
                                Cacc, NL3);
    k_agg<<<dim3(N, 1), 64, 0, stream>>>(hfbf, LD3, asrc, adst, csr_src, offsets,
                                         nullptr, nullptr, nullptr, b3, h3,
                                         HS3, NCLS, H3, 2);
  }

  // ---- Pool + log_softmax
  k_pool<<<64, dim3(64, 4), 0, stream>>>(h3, pooled, N);
  k_final<<<1, 64, 0, stream>>>(pooled, out);
}